// Round 12
// baseline (35944.022 us; speedup 1.0000x reference)
//
#include <hip/hip_runtime.h>
#include <math.h>

#define B_  32
#define T_  512
#define H_  512
#define A_  128
#define VD_ 512
#define V_  32000
#define GRID 1024
#define NCHUNK 1000   // 32-v logits chunks

__device__ __forceinline__ float sigf(float x){ return 1.f/(1.f+expf(-x)); }
__device__ __forceinline__ float dot4(float4 a, float4 b){ return a.x*b.x+a.y*b.y+a.z*b.z+a.w*b.w; }

struct DecArgs {
  const float *key, *value, *W_emb, *b_proj, *Wq, *bq, *W_ih, *W_hh, *b_ih, *b_hh, *Wm, *bm, *h00, *c00;
  const int* src_lens;
  float* out;
  float *hA, *hB, *c, *ctx, *projT, *logits, *lse, *pm, *ps;
  int *pidx, *idx;
  int* bar;   // [g*64] 32 group arrive cnts; [2048] master cnt; [2112] master gen;
              // [2176+g*64] 32 group gen lines; [4224] PD done counter
  int L;
};

// ---- hierarchical device barrier: 32 groups x 32 blocks, distributed release lines
__device__ __forceinline__ void gbar(int* bar) {
  __syncthreads();
  if (threadIdx.x == 0) {
    int grp = blockIdx.x & 31;
    int* gcnt = bar + grp*64;
    int* ggen = bar + 2176 + grp*64;
    int* mgen = bar + 2112;
    int g0 = __hip_atomic_load(ggen, __ATOMIC_RELAXED, __HIP_MEMORY_SCOPE_AGENT);
    int t = __hip_atomic_fetch_add(gcnt, 1, __ATOMIC_RELEASE, __HIP_MEMORY_SCOPE_AGENT);
    if (t == 31) {                 // group leader (last arrival of this group)
      __hip_atomic_store(gcnt, 0, __ATOMIC_RELAXED, __HIP_MEMORY_SCOPE_AGENT);
      int m0 = __hip_atomic_load(mgen, __ATOMIC_RELAXED, __HIP_MEMORY_SCOPE_AGENT);
      int tm = __hip_atomic_fetch_add(bar + 2048, 1, __ATOMIC_ACQ_REL, __HIP_MEMORY_SCOPE_AGENT);
      if (tm == 31) {              // final leader: release master
        __hip_atomic_store(bar + 2048, 0, __ATOMIC_RELAXED, __HIP_MEMORY_SCOPE_AGENT);
        __hip_atomic_fetch_add(mgen, 1, __ATOMIC_RELEASE, __HIP_MEMORY_SCOPE_AGENT);
      } else {                     // other leaders: poll master gen (<=32 pollers)
        int it = 0;
        while (__hip_atomic_load(mgen, __ATOMIC_RELAXED, __HIP_MEMORY_SCOPE_AGENT) == m0) {
          __builtin_amdgcn_s_sleep(4);
          if (++it > 8000) {
            while (__hip_atomic_load(mgen, __ATOMIC_ACQUIRE, __HIP_MEMORY_SCOPE_AGENT) == m0)
              __builtin_amdgcn_s_sleep(32);
            break;
          }
        }
      }
      __hip_atomic_fetch_add(ggen, 1, __ATOMIC_RELEASE, __HIP_MEMORY_SCOPE_AGENT);
      (void)__hip_atomic_load(mgen, __ATOMIC_ACQUIRE, __HIP_MEMORY_SCOPE_AGENT);
    } else {                       // non-leader: poll group-local gen (<=31 pollers)
      int it = 0;
      while (__hip_atomic_load(ggen, __ATOMIC_RELAXED, __HIP_MEMORY_SCOPE_AGENT) == g0) {
        __builtin_amdgcn_s_sleep(8);
        if (++it > 4000) {
          while (__hip_atomic_load(ggen, __ATOMIC_ACQUIRE, __HIP_MEMORY_SCOPE_AGENT) == g0)
            __builtin_amdgcn_s_sleep(32);
          break;
        }
      }
      (void)__hip_atomic_load(ggen, __ATOMIC_ACQUIRE, __HIP_MEMORY_SCOPE_AGENT);
    }
  }
  __syncthreads();
}

// ---------------- PA: gates+cell (blocks 0..511, 1 t-col) || out[s-1] (512..1023)
__device__ __forceinline__ void phaseA(const DecArgs& P, const float* hin, float* hout,
                                       int bid, int tid, int s, float* sm) {
  if (bid < 512) {
    float* sf  = sm;         // 256
    float* gsh = sm + 256;   // 128
    int g = tid >> 6, kh = (tid >> 5) & 1, b = tid & 31;
    int j = g*512 + bid;
    const float4* wi4  = (const float4*)(P.W_ih + (size_t)j*1024);
    const float4* wh4  = (const float4*)(P.W_hh + (size_t)j*512);
    const float4* emb4 = (const float4*)(P.W_emb + (size_t)P.idx[b]*512);
    const float4* ctx4 = (const float4*)(P.ctx + b*512);
    const float4* h4   = (const float4*)(hin + b*512);
    float acc = 0.f;
    int lo = kh*192, hi = lo + 192;
    for (int fi = lo; fi < hi; fi++) {
      float4 x4 = (fi < 128) ? emb4[fi] : (fi < 256) ? ctx4[fi-128] : h4[fi-256];
      float4 w4 = (fi < 256) ? wi4[fi] : wh4[fi-256];
      acc += dot4(w4, x4);
    }
    sf[tid] = acc;
    __syncthreads();
    if (tid < 128) {
      int gq = tid >> 5, b2 = tid & 31;
      int j2 = gq*512 + bid;
      gsh[gq*32 + b2] = sf[gq*64 + b2] + sf[gq*64 + 32 + b2] + P.b_ih[j2] + P.b_hh[j2];
    }
    __syncthreads();
    if (tid < 32) {
      int b3 = tid;
      float gi = gsh[b3], gf = gsh[32+b3], gg = gsh[64+b3], go = gsh[96+b3];
      float c0 = P.c[b3*512 + bid];
      float c1 = sigf(gf)*c0 + sigf(gi)*tanhf(gg);
      P.c[b3*512 + bid] = c1;
      hout[b3*512 + bid] = sigf(go)*tanhf(c1);
    }
  } else if (s > 0) {
    int r = bid - 512;
    int bb = r >> 4, vs = r & 15;
    float l = P.lse[bb];
    const float4* lg = (const float4*)(P.logits + (size_t)bb*V_ + vs*2000);
    float4* o4 = (float4*)(P.out + ((size_t)bb*P.L + (s-1))*V_ + vs*2000);
    for (int i = tid; i < 500; i += 256) {
      float4 x = lg[i];
      o4[i] = make_float4(x.x-l, x.y-l, x.z-l, x.w-l);
    }
  }
}

// ---------------- PB: q + energy + masked softmax + ctx 32-col slice (blocks 0..511)
// block = vs*32 + b ; vs 0..15
__device__ __forceinline__ void phaseB(const DecArgs& P, const float* hsrc,
                                       int bid, int tid, float* sf) {
  if (bid >= 512) return;
  int b = bid & 31, vs = bid >> 5;
  float* h_sh   = sf;         // 512
  float* q_sh   = sf + 512;   // 128
  float* red    = sf + 640;   // 256
  float* att_sh = sf + 896;   // 512
  h_sh[tid]       = hsrc[b*H_ + tid];
  h_sh[tid + 256] = hsrc[b*H_ + tid + 256];
  __syncthreads();
  if (tid < 128) {
    const float4* hv = (const float4*)h_sh;
    const float4* w  = (const float4*)(P.Wq + (size_t)tid*H_);
    float acc = P.bq[tid];
#pragma unroll 8
    for (int k = 0; k < 128; k++) acc += dot4(w[k], hv[k]);
    q_sh[tid] = acc;
  }
  __syncthreads();
  const float* kp = P.key + (size_t)b*A_*T_;
  float e0 = 0.f, e1 = 0.f;
#pragma unroll 8
  for (int a = 0; a < A_; a++) {
    float qa = q_sh[a];
    e0 += qa * kp[a*T_ + tid];
    e1 += qa * kp[a*T_ + tid + 256];
  }
  red[tid] = fmaxf(e0, e1);
  __syncthreads();
  for (int s2 = 128; s2 > 0; s2 >>= 1) { if (tid < s2) red[tid] = fmaxf(red[tid], red[tid+s2]); __syncthreads(); }
  float M = red[0];
  __syncthreads();
  int len = P.src_lens[b];
  float p0 = (tid       < len) ? expf(e0 - M) : 0.f;
  float p1 = (tid + 256 < len) ? expf(e1 - M) : 0.f;
  red[tid] = p0 + p1;
  __syncthreads();
  for (int s2 = 128; s2 > 0; s2 >>= 1) { if (tid < s2) red[tid] += red[tid+s2]; __syncthreads(); }
  float S = red[0];
  __syncthreads();
  att_sh[tid]       = p0 / S;
  att_sh[tid + 256] = p1 / S;
  __syncthreads();
  int vl = tid & 31, tq = tid >> 5;        // 8 t-groups of 64
  const float* vp = P.value + (size_t)b*T_*VD_ + vs*32 + vl;
  float acc = 0.f;
  int t0 = tq*64;
#pragma unroll 8
  for (int t = t0; t < t0 + 64; t++) acc += att_sh[t] * vp[(size_t)t*VD_];
  red[tid] = acc;
  __syncthreads();
  if (tid < 32) {
    float s2 = 0.f;
#pragma unroll
    for (int j = 0; j < 8; j++) s2 += red[j*32 + tid];
    P.ctx[b*VD_ + vs*32 + tid] = s2;
  }
}

// ---------------- PC: projT[m*32+b] (blocks 0..127, 4 m each)
__device__ __forceinline__ void phaseC(const DecArgs& P, int bid, int tid, float* sm) {
  if (bid >= 128) return;
  float* sf = sm;   // 256
  int ml = tid >> 6, kh = (tid >> 5) & 1, b = tid & 31;
  int m = bid*4 + ml;
  const float4* wm4 = (const float4*)(P.Wm + (size_t)m*1024);
  const float4* c4  = (const float4*)(P.c + b*512);
  const float4* x4  = (const float4*)(P.ctx + b*512);
  float acc = 0.f;
  int lo = kh*128, hi = lo + 128;
  for (int fi = lo; fi < hi; fi++) {
    float4 xv = (fi < 128) ? c4[fi] : x4[fi-128];
    acc += dot4(wm4[fi], xv);
  }
  sf[tid] = acc;
  __syncthreads();
  if (tid < 128) {
    int ml2 = tid >> 5, b2 = tid & 31;
    int m2 = bid*4 + ml2;
    float s = sf[ml2*64 + b2] + sf[ml2*64 + 32 + b2] + P.bm[m2];
    P.projT[m2*32 + b2] = (s > 0.f) ? s : 0.01f*s;
  }
}

// ---------------- merge all chunk partials -> lse/idx (one block, 256 thr)
__device__ __forceinline__ void merge_all(const DecArgs& P, int tid, float* sm) {
  int b = tid >> 3, g = tid & 7;
  float M = -INFINITY, S = 0.f; int I = 0x7fffffff;
  for (int ch = g; ch < NCHUNK; ch += 8) {
    float m2 = P.pm[ch*32+b], s2 = P.ps[ch*32+b]; int i2 = P.pidx[ch*32+b];
    if (m2 > M)       { S = S*expf(M-m2) + s2; M = m2; I = i2; }
    else if (m2 == M) { S += s2; I = min(I, i2); }
    else              { S += s2*expf(m2-M); }
  }
  float* mm = sm; float* ss = sm + 256; int* ii = (int*)(sm + 512);
  mm[tid] = M; ss[tid] = S; ii[tid] = I;
  __syncthreads();
  if (g == 0) {
    for (int j = 1; j < 8; j++) {
      float m2 = mm[b*8+j], s2 = ss[b*8+j]; int i2 = ii[b*8+j];
      if (m2 > M)       { S = S*expf(M-m2) + s2; M = m2; I = i2; }
      else if (m2 == M) { S += s2; I = min(I, i2); }
      else              { S += s2*expf(m2-M); }
    }
    P.lse[b] = M + logf(S);
    P.idx[b] = I;
  }
}

// ---------------- PD: logits chunk (32 v), prefetched staging, reg tile 4v x 8b
__device__ __forceinline__ void phaseD(const DecArgs& P, int bid, int tid, float* sm) {
  if (bid >= NCHUNK) return;
  const int v0 = bid * 32;
  float* Wl   = sm;            // [64][37] = 2368
  float* pl   = sm + 2368;     // [64][32] = 2048
  float* part = sm + 4416;     // [32][37] = 1184
  const int sr = tid >> 3, skq = tid & 7;
  const int kp = tid >> 5, vg = (tid >> 2) & 7, bg = tid & 3;
  float acc[32];
#pragma unroll
  for (int i = 0; i < 32; i++) acc[i] = 0.f;

  const float4* wbase = (const float4*)(P.W_emb + (size_t)(v0 + sr)*H_);   // pitch 128 f4
  const float4* pbase = (const float4*)P.projT;                            // 512x32 k-major
  float4 t0 = wbase[skq*2], t1 = wbase[skq*2 + 1];
  float4 u0 = pbase[tid],   u1 = pbase[tid + 256];

  for (int w = 0; w < 8; w++) {
    __syncthreads();
    int kb = skq*8;
    Wl[(kb+0)*37+sr]=t0.x; Wl[(kb+1)*37+sr]=t0.y; Wl[(kb+2)*37+sr]=t0.z; Wl[(kb+3)*37+sr]=t0.w;
    Wl[(kb+4)*37+sr]=t1.x; Wl[(kb+5)*37+sr]=t1.y; Wl[(kb+6)*37+sr]=t1.z; Wl[(kb+7)*37+sr]=t1.w;
    ((float4*)pl)[tid]       = u0;
    ((float4*)pl)[tid + 256] = u1;
    __syncthreads();
    if (w < 7) {   // prefetch next window while computing this one
      t0 = wbase[(w+1)*16 + skq*2];
      t1 = wbase[(w+1)*16 + skq*2 + 1];
      u0 = pbase[(w+1)*512 + tid];
      u1 = pbase[(w+1)*512 + tid + 256];
    }
#pragma unroll
    for (int kk = 0; kk < 8; kk++) {
      int kl = kp*8 + kk;
      float4 wv  = *((const float4*)(Wl + kl*37 + vg*4));
      float4 pv0 = *((const float4*)(pl + kl*32 + bg*8));
      float4 pv1 = *((const float4*)(pl + kl*32 + bg*8 + 4));
      float wa[4] = {wv.x, wv.y, wv.z, wv.w};
      float pa[8] = {pv0.x,pv0.y,pv0.z,pv0.w,pv1.x,pv1.y,pv1.z,pv1.w};
#pragma unroll
      for (int i = 0; i < 4; i++)
#pragma unroll
        for (int j = 0; j < 8; j++)
          acc[i*8+j] += wa[i]*pa[j];
    }
  }
  __syncthreads();
  if (kp == 0) {
#pragma unroll
    for (int j = 0; j < 8; j++) {
      int b = bg*8 + j;
      *((float4*)(part + b*37 + vg*4)) =
        make_float4(acc[0*8+j], acc[1*8+j], acc[2*8+j], acc[3*8+j]);
    }
  }
  __syncthreads();
  for (int rd = 1; rd < 8; rd++) {
    if (kp == rd) {
#pragma unroll
      for (int j = 0; j < 8; j++) {
        int b = bg*8 + j;
        float4* q0 = (float4*)(part + b*37 + vg*4);
        float4 a0 = *q0;
        a0.x += acc[0*8+j]; a0.y += acc[1*8+j]; a0.z += acc[2*8+j]; a0.w += acc[3*8+j];
        *q0 = a0;
      }
    }
    __syncthreads();
  }
  int b = tid >> 3, vq = tid & 7;
  float4 pA = *((const float4*)(part + b*37 + vq*4));
  int vb = v0 + vq*4;
  float x[4] = {pA.x, pA.y, pA.z, pA.w};
#pragma unroll
  for (int i = 0; i < 4; i++) x[i] += P.b_proj[vb + i];
  *((float4*)(P.logits + (size_t)b*V_ + vb)) = make_float4(x[0],x[1],x[2],x[3]);
  float m = x[0], s = 1.f; int mi = vb;
#pragma unroll
  for (int i = 1; i < 4; i++) {
    if (x[i] > m) { s = s*expf(m - x[i]) + 1.f; m = x[i]; mi = vb + i; }
    else          { s += expf(x[i] - m); }
  }
  float* rm = sm + 5600; float* rs = sm + 5856; int* ri = (int*)(sm + 6112);
  rm[vq*32 + b] = m; rs[vq*32 + b] = s; ri[vq*32 + b] = mi;
  __syncthreads();
  if (tid < 32) {
    int bb = tid;
    float M = rm[bb], S = rs[bb]; int I = ri[bb];
#pragma unroll
    for (int g = 1; g < 8; g++) {
      float m2 = rm[g*32+bb], s2 = rs[g*32+bb]; int i2 = ri[g*32+bb];
      if (m2 > M)       { S = S*expf(M - m2) + s2; M = m2; I = i2; }
      else if (m2 == M) { S += s2; I = min(I, i2); }
      else              { S += s2*expf(m2 - M); }
    }
    P.pm[bid*32 + bb] = M; P.ps[bid*32 + bb] = S; P.pidx[bid*32 + bb] = I;
  }
  __syncthreads();
  if (tid == 0) {
    int dc = __hip_atomic_fetch_add(P.bar + 4224, 1, __ATOMIC_ACQ_REL, __HIP_MEMORY_SCOPE_AGENT);
    ((int*)sm)[0] = (dc == NCHUNK - 1) ? 1 : 0;
  }
  __syncthreads();
  int last = ((int*)sm)[0];
  __syncthreads();
  if (last) {
    merge_all(P, tid, sm);
    __syncthreads();
    if (tid == 0) __hip_atomic_store(P.bar + 4224, 0, __ATOMIC_RELAXED, __HIP_MEMORY_SCOPE_AGENT);
  }
}

// ---------------- final out write (step L-1), 1024 blocks
__device__ __forceinline__ void phase_out_final(const DecArgs& P, int bid, int tid) {
  int b = bid & 31, ts = bid >> 5;   // 32 slices of 1000
  float l = P.lse[b];
  const float4* lg = (const float4*)(P.logits + (size_t)b*V_ + ts*1000);
  float4* o4 = (float4*)(P.out + ((size_t)b*P.L + (P.L-1))*V_ + ts*1000);
  for (int i = tid; i < 250; i += 256) {
    float4 x = lg[i];
    o4[i] = make_float4(x.x-l, x.y-l, x.z-l, x.w-l);
  }
}

__global__ __launch_bounds__(256, 4) void k_decode(DecArgs P) {
  const int bid = blockIdx.x, tid = threadIdx.x;
  __shared__ float sm[6368];   // 25.5 KB -> 4 blocks/CU by LDS

  int g = bid*256 + tid;
  if (g < B_*H_) { P.hA[g] = P.h00[g & (H_-1)]; P.c[g] = P.c00[g & (H_-1)]; }
  if (g < B_) P.idx[g] = 0;
  gbar(P.bar);

  phaseB(P, P.hA, bid, tid, sm);   // prologue attend with h0
  gbar(P.bar);

  for (int s = 0; s < P.L; s++) {
    const float* hin  = (s & 1) ? P.hB : P.hA;
    float*       hout = (s & 1) ? P.hA : P.hB;
    phaseA(P, hin, hout, bid, tid, s, sm);
    gbar(P.bar);
    phaseB(P, hout, bid, tid, sm);
    gbar(P.bar);
    phaseC(P, bid, tid, sm);
    gbar(P.bar);
    phaseD(P, bid, tid, sm);
    gbar(P.bar);
  }
  phase_out_final(P, bid, tid);
}

extern "C" void kernel_launch(void* const* d_in, const int* in_sizes, int n_in,
                              void* d_out, int out_size, void* d_ws, size_t ws_size,
                              hipStream_t stream) {
  DecArgs P;
  P.key      = (const float*)d_in[0];
  P.value    = (const float*)d_in[1];
  P.src_lens = (const int*)d_in[4];
  P.W_emb    = (const float*)d_in[5];
  P.b_proj   = (const float*)d_in[6];
  P.Wq       = (const float*)d_in[7];
  P.bq       = (const float*)d_in[8];
  P.W_ih     = (const float*)d_in[9];
  P.W_hh     = (const float*)d_in[10];
  P.b_ih     = (const float*)d_in[11];
  P.b_hh     = (const float*)d_in[12];
  P.Wm       = (const float*)d_in[13];
  P.bm       = (const float*)d_in[14];
  P.h00      = (const float*)d_in[15];
  P.c00      = (const float*)d_in[16];
  P.out      = (float*)d_out;
  P.L        = in_sizes[2] / B_;

  P.bar = (int*)d_ws;                       // 8192 ints reserved
  float* ws = (float*)d_ws + 8192;
  P.hA     = ws; ws += B_*H_;
  P.hB     = ws; ws += B_*H_;
  P.c      = ws; ws += B_*H_;
  P.ctx    = ws; ws += B_*VD_;
  P.projT  = ws; ws += H_*B_;
  P.lse    = ws; ws += 32;
  P.pm     = ws; ws += NCHUNK*B_;
  P.ps     = ws; ws += NCHUNK*B_;
  P.logits = ws; ws += (size_t)B_*V_;
  P.pidx   = (int*)ws; ws += NCHUNK*B_;
  P.idx    = (int*)ws;

  hipMemsetAsync(P.bar, 0, 8192*sizeof(int), stream);
  hipLaunchKernelGGL(k_decode, dim3(GRID), dim3(256), 0, stream, P);
}

// Round 13
// 22951.797 us; speedup vs baseline: 1.5661x; 1.5661x over previous
//
#include <hip/hip_runtime.h>
#include <math.h>

#define B_  32
#define T_  512
#define H_  512
#define A_  128
#define VD_ 512
#define V_  32000
#define GRID 512
#define NCHUNK 500   // 64-v logits chunks

__device__ __forceinline__ float sigf(float x){ return 1.f/(1.f+expf(-x)); }
__device__ __forceinline__ float dot4(float4 a, float4 b){ return a.x*b.x+a.y*b.y+a.z*b.z+a.w*b.w; }

// ---- agent-scope coherent word access (bypasses stale caches, invalidates nothing)
__device__ __forceinline__ float ldf(const float* p){
  return __hip_atomic_load(const_cast<float*>(p), __ATOMIC_RELAXED, __HIP_MEMORY_SCOPE_AGENT);
}
__device__ __forceinline__ void stf(float* p, float v){
  __hip_atomic_store(p, v, __ATOMIC_RELAXED, __HIP_MEMORY_SCOPE_AGENT);
}
__device__ __forceinline__ int ldi(const int* p){
  return __hip_atomic_load(const_cast<int*>(p), __ATOMIC_RELAXED, __HIP_MEMORY_SCOPE_AGENT);
}
__device__ __forceinline__ void sti(int* p, int v){
  __hip_atomic_store(p, v, __ATOMIC_RELAXED, __HIP_MEMORY_SCOPE_AGENT);
}

struct DecArgs {
  const float *key, *value, *W_emb, *b_proj, *Wq, *bq, *W_ih, *W_hh, *b_ih, *b_hh, *Wm, *bm, *h00, *c00;
  const int* src_lens;
  float* out;
  float *hA, *hB, *c, *ctx, *projT, *logits, *lse, *pm, *ps;
  int *pidx, *idx;
  int* bar;
  int L;
};

// ---- hierarchical barrier, 16 groups x 32 blocks: RELEASE arrivals, RELAXED polls,
// ---- NO acquire (cross-block data moves via ldf/stf, so caches need no invalidate).
__device__ __forceinline__ void gbar(int* bar) {
  __syncthreads();
  if (threadIdx.x == 0) {
    int grp = blockIdx.x & 15;
    int* gcnt = bar + grp*64;
    int* ggen = bar + 1152 + grp*64;
    int* mgen = bar + 1088;
    int g0 = __hip_atomic_load(ggen, __ATOMIC_RELAXED, __HIP_MEMORY_SCOPE_AGENT);
    int t = __hip_atomic_fetch_add(gcnt, 1, __ATOMIC_RELEASE, __HIP_MEMORY_SCOPE_AGENT);
    if (t == 31) {
      __hip_atomic_store(gcnt, 0, __ATOMIC_RELAXED, __HIP_MEMORY_SCOPE_AGENT);
      int m0 = __hip_atomic_load(mgen, __ATOMIC_RELAXED, __HIP_MEMORY_SCOPE_AGENT);
      int tm = __hip_atomic_fetch_add(bar + 1024, 1, __ATOMIC_RELEASE, __HIP_MEMORY_SCOPE_AGENT);
      if (tm == 15) {
        __hip_atomic_store(bar + 1024, 0, __ATOMIC_RELAXED, __HIP_MEMORY_SCOPE_AGENT);
        __hip_atomic_fetch_add(mgen, 1, __ATOMIC_RELEASE, __HIP_MEMORY_SCOPE_AGENT);
      } else {
        int it = 0;
        while (__hip_atomic_load(mgen, __ATOMIC_RELAXED, __HIP_MEMORY_SCOPE_AGENT) == m0) {
          __builtin_amdgcn_s_sleep(4);
          if (++it > 20000) break;
        }
      }
      __hip_atomic_fetch_add(ggen, 1, __ATOMIC_RELEASE, __HIP_MEMORY_SCOPE_AGENT);
    } else {
      int it = 0;
      while (__hip_atomic_load(ggen, __ATOMIC_RELAXED, __HIP_MEMORY_SCOPE_AGENT) == g0) {
        __builtin_amdgcn_s_sleep(8);
        if (++it > 20000) break;
      }
    }
    asm volatile("" ::: "memory");
  }
  __syncthreads();
}

// ---------------- PA: gates GEMM + cell (blocks 0..255) || out[s-1] (256..511)
__device__ __forceinline__ void phaseA(const DecArgs& P, const float* hin, float* hout,
                                       int bid, int tid, int s, float* sm) {
  if (bid < 256) {
    float* Wl   = sm;          // [64][9]  = 576
    float* xl   = sm + 576;    // [64][36] = 2304
    float* part = sm + 2880;   // [8][36]  = 288
    int*   idx_sh = (int*)(sm + 3168);   // 32
    const int kp = tid >> 5, jr = (tid >> 2) & 7, bg = tid & 3;
    if (tid < 32) idx_sh[tid] = ldi(P.idx + tid);
    float acc[8];
#pragma unroll
    for (int i = 0; i < 8; i++) acc[i] = 0.f;

    for (int w = 0; w < 24; w++) {
      __syncthreads();
      if (tid < 128) {   // stage W rows (const weights: normal cached loads)
        int r = tid >> 4, i = tid & 15;
        int g = r >> 1, tl = r & 1;
        int j = g*512 + bid*2 + tl;
        const float4* src = (w < 16)
          ? (const float4*)(P.W_ih + (size_t)j*1024) + w*16 + i
          : (const float4*)(P.W_hh + (size_t)j*512) + (w-16)*16 + i;
        float4 x = *src;
        int kb = i*4;
        Wl[(kb+0)*9+r]=x.x; Wl[(kb+1)*9+r]=x.y; Wl[(kb+2)*9+r]=x.z; Wl[(kb+3)*9+r]=x.w;
      }
      {  // stage x = [emb|ctx|h]: emb rows are const (normal), ctx/h are state (ldf)
        int q = tid*2;
#pragma unroll
        for (int u = 0; u < 2; u++, q++) {
          int b = q >> 4, i = q & 15;
          float4 x;
          if (w < 8) {
            x = *((const float4*)(P.W_emb + (size_t)idx_sh[b]*512) + w*16 + i);
          } else {
            const float* sp = (w < 16) ? (P.ctx + b*512 + (w-8)*64 + i*4)
                                       : (hin  + b*512 + (w-16)*64 + i*4);
            x = make_float4(ldf(sp), ldf(sp+1), ldf(sp+2), ldf(sp+3));
          }
          int kb = i*4;
          xl[(kb+0)*36+b]=x.x; xl[(kb+1)*36+b]=x.y; xl[(kb+2)*36+b]=x.z; xl[(kb+3)*36+b]=x.w;
        }
      }
      __syncthreads();
#pragma unroll
      for (int kk = 0; kk < 8; kk++) {
        int kl = kp*8 + kk;
        float wv = Wl[kl*9 + jr];
        const float4* xv = (const float4*)(xl + kl*36 + bg*8);
        float4 a0 = xv[0], a1 = xv[1];
        acc[0] += wv*a0.x; acc[1] += wv*a0.y; acc[2] += wv*a0.z; acc[3] += wv*a0.w;
        acc[4] += wv*a1.x; acc[5] += wv*a1.y; acc[6] += wv*a1.z; acc[7] += wv*a1.w;
      }
    }
    __syncthreads();
    for (int rd = 0; rd < 8; rd++) {
      if (kp == rd) {
        float* pr = part + jr*36 + bg*8;
        if (rd == 0) {
#pragma unroll
          for (int u = 0; u < 8; u++) pr[u] = acc[u];
        } else {
#pragma unroll
          for (int u = 0; u < 8; u++) pr[u] += acc[u];
        }
      }
      __syncthreads();
    }
    if (tid < 64) {   // LSTM cell epilogue (c, hout are cross-block state)
      int tl = tid >> 5, b = tid & 31;
      int t = bid*2 + tl;
      float gi = part[(0+tl)*36 + b] + P.b_ih[0*512+t] + P.b_hh[0*512+t];
      float gf = part[(2+tl)*36 + b] + P.b_ih[1*512+t] + P.b_hh[1*512+t];
      float gg = part[(4+tl)*36 + b] + P.b_ih[2*512+t] + P.b_hh[2*512+t];
      float go = part[(6+tl)*36 + b] + P.b_ih[3*512+t] + P.b_hh[3*512+t];
      float c0 = ldf(P.c + b*H_ + t);
      float c1 = sigf(gf)*c0 + sigf(gi)*tanhf(gg);
      stf(P.c + b*H_ + t, c1);
      stf(hout + b*H_ + t, sigf(go)*tanhf(c1));
    }
  } else if (s > 0) {
    int r = bid - 256;
    int bb = r >> 3, vs = r & 7;
    float l = ldf(P.lse + bb);
    const float* lg = P.logits + (size_t)bb*V_ + vs*4000;
    float4* o4 = (float4*)(P.out + ((size_t)bb*P.L + (s-1))*V_ + vs*4000);
    for (int i = tid; i < 1000; i += 256) {
      o4[i] = make_float4(ldf(lg+i*4)-l, ldf(lg+i*4+1)-l, ldf(lg+i*4+2)-l, ldf(lg+i*4+3)-l);
    }
  }
}

// ---------------- PB: q + energy + masked softmax + ctx 64-col slice (blocks 0..255)
__device__ __forceinline__ void phaseB(const DecArgs& P, const float* hsrc,
                                       int bid, int tid, float* sf) {
  if (bid >= 256) return;
  int b = bid & 31, vs = bid >> 5;
  float* h_sh   = sf;         // 512
  float* q_sh   = sf + 512;   // 128
  float* red    = sf + 640;   // 256
  float* att_sh = sf + 896;   // 512
  h_sh[tid]       = ldf(hsrc + b*H_ + tid);
  h_sh[tid + 256] = ldf(hsrc + b*H_ + tid + 256);
  __syncthreads();
  if (tid < 128) {
    const float4* hv = (const float4*)h_sh;
    const float4* w  = (const float4*)(P.Wq + (size_t)tid*H_);
    float acc = P.bq[tid];
#pragma unroll 8
    for (int k = 0; k < 128; k++) acc += dot4(w[k], hv[k]);
    q_sh[tid] = acc;
  }
  __syncthreads();
  const float* kp = P.key + (size_t)b*A_*T_;
  float e0 = 0.f, e1 = 0.f;
#pragma unroll 8
  for (int a = 0; a < A_; a++) {
    float qa = q_sh[a];
    e0 += qa * kp[a*T_ + tid];
    e1 += qa * kp[a*T_ + tid + 256];
  }
  red[tid] = fmaxf(e0, e1);
  __syncthreads();
  for (int s2 = 128; s2 > 0; s2 >>= 1) { if (tid < s2) red[tid] = fmaxf(red[tid], red[tid+s2]); __syncthreads(); }
  float M = red[0];
  __syncthreads();
  int len = P.src_lens[b];
  float p0 = (tid       < len) ? expf(e0 - M) : 0.f;
  float p1 = (tid + 256 < len) ? expf(e1 - M) : 0.f;
  red[tid] = p0 + p1;
  __syncthreads();
  for (int s2 = 128; s2 > 0; s2 >>= 1) { if (tid < s2) red[tid] += red[tid+s2]; __syncthreads(); }
  float S = red[0];
  __syncthreads();
  att_sh[tid]       = p0 / S;
  att_sh[tid + 256] = p1 / S;
  __syncthreads();
  int vl = tid & 63, tq = tid >> 6;
  int v = vs*64 + vl;
  const float* vp = P.value + (size_t)b*T_*VD_ + v;
  float acc = 0.f;
  int t0 = tq*128;
#pragma unroll 8
  for (int t = t0; t < t0 + 128; t++) acc += att_sh[t] * vp[(size_t)t*VD_];
  red[tid] = acc;
  __syncthreads();
  if (tid < 64) stf(P.ctx + b*VD_ + vs*64 + tid, red[tid] + red[tid+64] + red[tid+128] + red[tid+192]);
}

// ---------------- PC: proj GEMM (blocks 0..255, 2 m-rows each), K=1024, 16 windows
__device__ __forceinline__ void phaseC(const DecArgs& P, int bid, int tid, float* sm) {
  if (bid >= 256) return;
  float* Wl   = sm;          // [64][3]  = 192
  float* xl   = sm + 192;    // [64][36] = 2304
  float* part = sm + 2496;   // [2][36]  = 72
  const int kp = tid >> 5, ml = (tid >> 4) & 1, bg = tid & 15;
  float acc0 = 0.f, acc1 = 0.f;

  for (int w = 0; w < 16; w++) {
    __syncthreads();
    if (tid < 32) {   // stage 2 Wm rows (const: normal loads)
      int r = tid >> 4, i = tid & 15;
      const float4* src = (const float4*)(P.Wm + (size_t)(bid*2+r)*1024) + w*16 + i;
      float4 x = *src;
      int kb = i*4;
      Wl[(kb+0)*3+r]=x.x; Wl[(kb+1)*3+r]=x.y; Wl[(kb+2)*3+r]=x.z; Wl[(kb+3)*3+r]=x.w;
    }
    {  // stage x = [c|ctx] (cross-block state: ldf)
      int q = tid*2;
#pragma unroll
      for (int u = 0; u < 2; u++, q++) {
        int b = q >> 4, i = q & 15;
        const float* sp = (w < 8) ? (P.c + b*512 + w*64 + i*4)
                                  : (P.ctx + b*512 + (w-8)*64 + i*4);
        float4 x = make_float4(ldf(sp), ldf(sp+1), ldf(sp+2), ldf(sp+3));
        int kb = i*4;
        xl[(kb+0)*36+b]=x.x; xl[(kb+1)*36+b]=x.y; xl[(kb+2)*36+b]=x.z; xl[(kb+3)*36+b]=x.w;
      }
    }
    __syncthreads();
#pragma unroll
    for (int kk = 0; kk < 8; kk++) {
      int kl = kp*8 + kk;
      float wv = Wl[kl*3 + ml];
      acc0 += wv * xl[kl*36 + bg*2];
      acc1 += wv * xl[kl*36 + bg*2 + 1];
    }
  }
  __syncthreads();
  for (int rd = 0; rd < 8; rd++) {
    if (kp == rd) {
      float* pr = part + ml*36 + bg*2;
      if (rd == 0) { pr[0] = acc0; pr[1] = acc1; }
      else         { pr[0] += acc0; pr[1] += acc1; }
    }
    __syncthreads();
  }
  if (tid < 64) {
    int ml2 = tid >> 5, b = tid & 31;
    int m = bid*2 + ml2;
    float s = part[ml2*36 + b] + P.bm[m];
    stf(P.projT + m*32 + b, (s > 0.f) ? s : 0.01f*s);
  }
}

// ---------------- merge all chunk partials -> lse/idx (one block, 256 thr)
__device__ __forceinline__ void merge_all(const DecArgs& P, int tid, float* sm) {
  int b = tid >> 3, g = tid & 7;
  float M = -INFINITY, S = 0.f; int I = 0x7fffffff;
  for (int ch = g; ch < NCHUNK; ch += 8) {
    float m2 = ldf(P.pm + ch*32+b), s2 = ldf(P.ps + ch*32+b); int i2 = ldi(P.pidx + ch*32+b);
    if (m2 > M)       { S = S*expf(M-m2) + s2; M = m2; I = i2; }
    else if (m2 == M) { S += s2; I = min(I, i2); }
    else              { S += s2*expf(m2-M); }
  }
  float* mm = sm; float* ss = sm + 256; int* ii = (int*)(sm + 512);
  mm[tid] = M; ss[tid] = S; ii[tid] = I;
  __syncthreads();
  if (g == 0) {
    for (int j = 1; j < 8; j++) {
      float m2 = mm[b*8+j], s2 = ss[b*8+j]; int i2 = ii[b*8+j];
      if (m2 > M)       { S = S*expf(M-m2) + s2; M = m2; I = i2; }
      else if (m2 == M) { S += s2; I = min(I, i2); }
      else              { S += s2*expf(m2-M); }
    }
    stf(P.lse + b, M + logf(S));
    sti(P.idx + b, I);
  }
}

// ---------------- PD: logits chunk (64 v) reg-tiled GEMM, prefetched staging
__device__ __forceinline__ void phaseD(const DecArgs& P, int bid, int tid, float* sm) {
  if (bid >= NCHUNK) return;
  const int v0 = bid * 64;
  float* Wl   = sm;            // [64k][68]
  float* pl   = sm + 4352;     // [64k][32]
  float* part = sm + 6400;     // [32b][68]
  const int kp = tid >> 5, vg = (tid >> 2) & 7, bg = tid & 3;
  const int sr = tid >> 2, skq = tid & 3;
  float acc[64];
#pragma unroll
  for (int i = 0; i < 64; i++) acc[i] = 0.f;

  const float* wrow = P.W_emb + (size_t)(v0 + sr)*H_ + skq*16;   // const: normal loads
  float4 t0 = *((const float4*)(wrow + 0));
  float4 t1 = *((const float4*)(wrow + 4));
  float4 t2 = *((const float4*)(wrow + 8));
  float4 t3 = *((const float4*)(wrow + 12));
  float u[8];
#pragma unroll
  for (int j2 = 0; j2 < 4; j2++) {
    u[j2]   = ldf(P.projT + tid*4 + j2);          // state: coherent loads
    u[4+j2] = ldf(P.projT + 1024 + tid*4 + j2);
  }

  for (int w = 0; w < 8; w++) {
    __syncthreads();
    int kb = skq*16;
    Wl[(kb+ 0)*68+sr]=t0.x; Wl[(kb+ 1)*68+sr]=t0.y; Wl[(kb+ 2)*68+sr]=t0.z; Wl[(kb+ 3)*68+sr]=t0.w;
    Wl[(kb+ 4)*68+sr]=t1.x; Wl[(kb+ 5)*68+sr]=t1.y; Wl[(kb+ 6)*68+sr]=t1.z; Wl[(kb+ 7)*68+sr]=t1.w;
    Wl[(kb+ 8)*68+sr]=t2.x; Wl[(kb+ 9)*68+sr]=t2.y; Wl[(kb+10)*68+sr]=t2.z; Wl[(kb+11)*68+sr]=t2.w;
    Wl[(kb+12)*68+sr]=t3.x; Wl[(kb+13)*68+sr]=t3.y; Wl[(kb+14)*68+sr]=t3.z; Wl[(kb+15)*68+sr]=t3.w;
    float4* plv = (float4*)pl;
    plv[tid]       = make_float4(u[0], u[1], u[2], u[3]);
    plv[tid + 256] = make_float4(u[4], u[5], u[6], u[7]);
    __syncthreads();
    if (w < 7) {
      const float* wn = wrow + (w+1)*64;
      t0 = *((const float4*)(wn + 0));
      t1 = *((const float4*)(wn + 4));
      t2 = *((const float4*)(wn + 8));
      t3 = *((const float4*)(wn + 12));
#pragma unroll
      for (int j2 = 0; j2 < 4; j2++) {
        u[j2]   = ldf(P.projT + (w+1)*2048 + tid*4 + j2);
        u[4+j2] = ldf(P.projT + (w+1)*2048 + 1024 + tid*4 + j2);
      }
    }
#pragma unroll
    for (int kk = 0; kk < 8; kk++) {
      int kl = kp*8 + kk;
      float4 wv0 = *((const float4*)(Wl + kl*68 + vg*8));
      float4 wv1 = *((const float4*)(Wl + kl*68 + vg*8 + 4));
      float4 pv0 = *((const float4*)(pl + kl*32 + bg*8));
      float4 pv1 = *((const float4*)(pl + kl*32 + bg*8 + 4));
      float wa[8] = {wv0.x,wv0.y,wv0.z,wv0.w,wv1.x,wv1.y,wv1.z,wv1.w};
      float pa[8] = {pv0.x,pv0.y,pv0.z,pv0.w,pv1.x,pv1.y,pv1.z,pv1.w};
#pragma unroll
      for (int i = 0; i < 8; i++)
#pragma unroll
        for (int j = 0; j < 8; j++)
          acc[i*8+j] += wa[i]*pa[j];
    }
  }
  __syncthreads();
  if (kp == 0) {
#pragma unroll
    for (int j = 0; j < 8; j++) {
      int b = bg*8 + j;
      *((float4*)(part + b*68 + vg*8))     = make_float4(acc[0*8+j], acc[1*8+j], acc[2*8+j], acc[3*8+j]);
      *((float4*)(part + b*68 + vg*8 + 4)) = make_float4(acc[4*8+j], acc[5*8+j], acc[6*8+j], acc[7*8+j]);
    }
  }
  __syncthreads();
  for (int rd = 1; rd < 8; rd++) {
    if (kp == rd) {
#pragma unroll
      for (int j = 0; j < 8; j++) {
        int b = bg*8 + j;
        float4* q0 = (float4*)(part + b*68 + vg*8);
        float4* q1 = q0 + 1;
        float4 a0 = *q0, a1 = *q1;
        a0.x += acc[0*8+j]; a0.y += acc[1*8+j]; a0.z += acc[2*8+j]; a0.w += acc[3*8+j];
        a1.x += acc[4*8+j]; a1.y += acc[5*8+j]; a1.z += acc[6*8+j]; a1.w += acc[7*8+j];
        *q0 = a0; *q1 = a1;
      }
    }
    __syncthreads();
  }
  int b = tid >> 3, vq = tid & 7;
  float4 pA = *((const float4*)(part + b*68 + vq*8));
  float4 pB = *((const float4*)(part + b*68 + vq*8 + 4));
  int vb = v0 + vq*8;
  float x[8] = {pA.x,pA.y,pA.z,pA.w,pB.x,pB.y,pB.z,pB.w};
#pragma unroll
  for (int i = 0; i < 8; i++) x[i] += P.b_proj[vb + i];
#pragma unroll
  for (int i = 0; i < 8; i++) stf(P.logits + (size_t)b*V_ + vb + i, x[i]);
  float m = x[0], s = 1.f; int mi = vb;
#pragma unroll
  for (int i = 1; i < 8; i++) {
    if (x[i] > m) { s = s*expf(m - x[i]) + 1.f; m = x[i]; mi = vb + i; }
    else          { s += expf(x[i] - m); }
  }
  float* rm = sm + 8576; float* rs = sm + 8832; int* ri = (int*)(sm + 9088);
  rm[vq*32 + b] = m; rs[vq*32 + b] = s; ri[vq*32 + b] = mi;
  __syncthreads();
  if (tid < 32) {
    int bb = tid;
    float M = rm[bb], S = rs[bb]; int I = ri[bb];
#pragma unroll
    for (int g = 1; g < 8; g++) {
      float m2 = rm[g*32+bb], s2 = rs[g*32+bb]; int i2 = ri[g*32+bb];
      if (m2 > M)       { S = S*expf(M - m2) + s2; M = m2; I = i2; }
      else if (m2 == M) { S += s2; I = min(I, i2); }
      else              { S += s2*expf(m2 - M); }
    }
    stf(P.pm + bid*32 + bb, M); stf(P.ps + bid*32 + bb, S); sti(P.pidx + bid*32 + bb, I);
  }
  // in-phase merge: last chunk block merges all partials (RELEASE only; reads are ldf)
  __syncthreads();
  if (tid == 0) {
    int dc = __hip_atomic_fetch_add(P.bar + 2176, 1, __ATOMIC_RELEASE, __HIP_MEMORY_SCOPE_AGENT);
    ((int*)sm)[0] = (dc == NCHUNK - 1) ? 1 : 0;
    asm volatile("" ::: "memory");
  }
  __syncthreads();
  int last = ((int*)sm)[0];
  __syncthreads();
  if (last) {
    merge_all(P, tid, sm);
    __syncthreads();
    if (tid == 0) __hip_atomic_store(P.bar + 2176, 0, __ATOMIC_RELAXED, __HIP_MEMORY_SCOPE_AGENT);
  }
}

// ---------------- final out write (step L-1), 512 blocks
__device__ __forceinline__ void phase_out_final(const DecArgs& P, int bid, int tid) {
  int b = bid & 31, ts = bid >> 5;
  float l = ldf(P.lse + b);
  const float* lg = P.logits + (size_t)b*V_ + ts*2000;
  float4* o4 = (float4*)(P.out + ((size_t)b*P.L + (P.L-1))*V_ + ts*2000);
  for (int i = tid; i < 500; i += 256) {
    o4[i] = make_float4(ldf(lg+i*4)-l, ldf(lg+i*4+1)-l, ldf(lg+i*4+2)-l, ldf(lg+i*4+3)-l);
  }
}

__global__ __launch_bounds__(256, 2) void k_decode(DecArgs P) {
  const int bid = blockIdx.x, tid = threadIdx.x;
  __shared__ float sm[9600];   // 38.4 KB

  int g = bid*256 + tid;
  if (g < B_*H_) { stf(P.hA + g, P.h00[g & (H_-1)]); stf(P.c + g, P.c00[g & (H_-1)]); }
  if (g < B_) sti(P.idx + g, 0);
  gbar(P.bar);

  phaseB(P, P.hA, bid, tid, sm);   // prologue attend with h0
  gbar(P.bar);

  for (int s = 0; s < P.L; s++) {
    const float* hin  = (s & 1) ? P.hB : P.hA;
    float*       hout = (s & 1) ? P.hA : P.hB;
    phaseA(P, hin, hout, bid, tid, s, sm);
    gbar(P.bar);
    phaseB(P, hout, bid, tid, sm);
    gbar(P.bar);
    phaseC(P, bid, tid, sm);
    gbar(P.bar);
    phaseD(P, bid, tid, sm);
    gbar(P.bar);
  }
  phase_out_final(P, bid, tid);
}

extern "C" void kernel_launch(void* const* d_in, const int* in_sizes, int n_in,
                              void* d_out, int out_size, void* d_ws, size_t ws_size,
                              hipStream_t stream) {
  DecArgs P;
  P.key      = (const float*)d_in[0];
  P.value    = (const float*)d_in[1];
  P.src_lens = (const int*)d_in[4];
  P.W_emb    = (const float*)d_in[5];
  P.b_proj   = (const float*)d_in[6];
  P.Wq       = (const float*)d_in[7];
  P.bq       = (const float*)d_in[8];
  P.W_ih     = (const float*)d_in[9];
  P.W_hh     = (const float*)d_in[10];
  P.b_ih     = (const float*)d_in[11];
  P.b_hh     = (const float*)d_in[12];
  P.Wm       = (const float*)d_in[13];
  P.bm       = (const float*)d_in[14];
  P.h00      = (const float*)d_in[15];
  P.c00      = (const float*)d_in[16];
  P.out      = (float*)d_out;
  P.L        = in_sizes[2] / B_;

  P.bar = (int*)d_ws;                       // 4096 ints reserved
  float* ws = (float*)d_ws + 4096;
  P.hA     = ws; ws += B_*H_;
  P.hB     = ws; ws += B_*H_;
  P.c      = ws; ws += B_*H_;
  P.ctx    = ws; ws += B_*VD_;
  P.projT  = ws; ws += H_*B_;
  P.lse    = ws; ws += 32;
  P.pm     = ws; ws += NCHUNK*B_;
  P.ps     = ws; ws += NCHUNK*B_;
  P.logits = ws; ws += (size_t)B_*V_;
  P.pidx   = (int*)ws; ws += NCHUNK*B_;
  P.idx    = (int*)ws;

  hipMemsetAsync(P.bar, 0, 4096*sizeof(int), stream);
  hipLaunchKernelGGL(k_decode, dim3(GRID), dim3(256), 0, stream, P);
}

// Round 14
// 10081.912 us; speedup vs baseline: 3.5652x; 2.2765x over previous
//
#include <hip/hip_runtime.h>
#include <math.h>

#define B_  32
#define T_  512
#define H_  512
#define A_  128
#define VD_ 512
#define V_  32000
#define NCHUNK 500   // 64-v logits chunks

__device__ __forceinline__ float sigf(float x){ return 1.f/(1.f+expf(-x)); }
__device__ __forceinline__ float dot4(float4 a, float4 b){ return a.x*b.x+a.y*b.y+a.z*b.z+a.w*b.w; }

struct DecArgs {
  const float *key, *value, *W_emb, *b_proj, *Wq, *bq, *W_ih, *W_hh, *b_ih, *b_hh, *Wm, *bm, *h00, *c00;
  const int* src_lens;
  float* out;
  float *hA, *hB, *c, *ctx, *projT, *logits, *lse, *pm, *ps;
  int *pidx, *idx;
  int L;
};

// ---------------- init h, c, idx
__global__ void k_init(DecArgs P) {
  int g = blockIdx.x*256 + threadIdx.x;
  if (g < B_*H_) { P.hA[g] = P.h00[g & (H_-1)]; P.c[g] = P.c00[g & (H_-1)]; }
  if (g < B_) P.idx[g] = 0;
}

// ---------------- gates GEMM + LSTM cell (blocks 0..255) || out[s-1] (256..511)
__global__ __launch_bounds__(256) void k_gatesout(DecArgs P, const float* hin,
                                                  float* hout, int s) {
  __shared__ float sm[3200];
  int bid = blockIdx.x, tid = threadIdx.x;
  if (bid < 256) {
    float* Wl   = sm;          // [64][9]  = 576
    float* xl   = sm + 576;    // [64][36] = 2304
    float* part = sm + 2880;   // [8][36]  = 288
    int*   idx_sh = (int*)(sm + 3168);
    const int kp = tid >> 5, jr = (tid >> 2) & 7, bg = tid & 3;
    if (tid < 32) idx_sh[tid] = P.idx[tid];
    float acc[8];
#pragma unroll
    for (int i = 0; i < 8; i++) acc[i] = 0.f;

    for (int w = 0; w < 24; w++) {
      __syncthreads();
      if (tid < 128) {
        int r = tid >> 4, i = tid & 15;
        int g = r >> 1, tl = r & 1;
        int j = g*512 + bid*2 + tl;
        const float4* src = (w < 16)
          ? (const float4*)(P.W_ih + (size_t)j*1024) + w*16 + i
          : (const float4*)(P.W_hh + (size_t)j*512) + (w-16)*16 + i;
        float4 x = *src;
        int kb = i*4;
        Wl[(kb+0)*9+r]=x.x; Wl[(kb+1)*9+r]=x.y; Wl[(kb+2)*9+r]=x.z; Wl[(kb+3)*9+r]=x.w;
      }
      {
        int q = tid*2;
#pragma unroll
        for (int u = 0; u < 2; u++, q++) {
          int b = q >> 4, i = q & 15;
          float4 x;
          if (w < 8)       x = *((const float4*)(P.W_emb + (size_t)idx_sh[b]*512) + w*16 + i);
          else if (w < 16) x = *((const float4*)(P.ctx + b*512) + (w-8)*16 + i);
          else             x = *((const float4*)(hin  + b*512) + (w-16)*16 + i);
          int kb = i*4;
          xl[(kb+0)*36+b]=x.x; xl[(kb+1)*36+b]=x.y; xl[(kb+2)*36+b]=x.z; xl[(kb+3)*36+b]=x.w;
        }
      }
      __syncthreads();
#pragma unroll
      for (int kk = 0; kk < 8; kk++) {
        int kl = kp*8 + kk;
        float wv = Wl[kl*9 + jr];
        const float4* xv = (const float4*)(xl + kl*36 + bg*8);
        float4 a0 = xv[0], a1 = xv[1];
        acc[0] += wv*a0.x; acc[1] += wv*a0.y; acc[2] += wv*a0.z; acc[3] += wv*a0.w;
        acc[4] += wv*a1.x; acc[5] += wv*a1.y; acc[6] += wv*a1.z; acc[7] += wv*a1.w;
      }
    }
    __syncthreads();
    for (int rd = 0; rd < 8; rd++) {
      if (kp == rd) {
        float* pr = part + jr*36 + bg*8;
        if (rd == 0) {
#pragma unroll
          for (int u = 0; u < 8; u++) pr[u] = acc[u];
        } else {
#pragma unroll
          for (int u = 0; u < 8; u++) pr[u] += acc[u];
        }
      }
      __syncthreads();
    }
    if (tid < 64) {
      int tl = tid >> 5, b = tid & 31;
      int t = bid*2 + tl;
      float gi = part[(0+tl)*36 + b] + P.b_ih[0*512+t] + P.b_hh[0*512+t];
      float gf = part[(2+tl)*36 + b] + P.b_ih[1*512+t] + P.b_hh[1*512+t];
      float gg = part[(4+tl)*36 + b] + P.b_ih[2*512+t] + P.b_hh[2*512+t];
      float go = part[(6+tl)*36 + b] + P.b_ih[3*512+t] + P.b_hh[3*512+t];
      float c0 = P.c[b*H_ + t];
      float c1 = sigf(gf)*c0 + sigf(gi)*tanhf(gg);
      P.c[b*H_ + t] = c1;
      hout[b*H_ + t] = sigf(go)*tanhf(c1);
    }
  } else if (s > 0) {
    int r = bid - 256;
    int bb = r >> 3, vs = r & 7;
    float l = P.lse[bb];
    const float4* lg = (const float4*)(P.logits + (size_t)bb*V_ + vs*4000);
    float4* o4 = (float4*)(P.out + ((size_t)bb*P.L + (s-1))*V_ + vs*4000);
    for (int i = tid; i < 1000; i += 256) {
      float4 x = lg[i];
      o4[i] = make_float4(x.x-l, x.y-l, x.z-l, x.w-l);
    }
  }
}

// ---------------- q + energy + masked softmax + ctx 64-col slice (256 blocks)
__global__ __launch_bounds__(256) void k_att(DecArgs P, const float* hsrc) {
  __shared__ float sf[1408];
  int bid = blockIdx.x, tid = threadIdx.x;
  int b = bid & 31, vs = bid >> 5;
  float* h_sh   = sf;         // 512
  float* q_sh   = sf + 512;   // 128
  float* red    = sf + 640;   // 256
  float* att_sh = sf + 896;   // 512
  h_sh[tid]       = hsrc[b*H_ + tid];
  h_sh[tid + 256] = hsrc[b*H_ + tid + 256];
  __syncthreads();
  if (tid < 128) {
    const float4* hv = (const float4*)h_sh;
    const float4* w  = (const float4*)(P.Wq + (size_t)tid*H_);
    float acc = P.bq[tid];
#pragma unroll 8
    for (int k = 0; k < 128; k++) acc += dot4(w[k], hv[k]);
    q_sh[tid] = acc;
  }
  __syncthreads();
  const float* kp = P.key + (size_t)b*A_*T_;
  float e0 = 0.f, e1 = 0.f;
#pragma unroll 8
  for (int a = 0; a < A_; a++) {
    float qa = q_sh[a];
    e0 += qa * kp[a*T_ + tid];
    e1 += qa * kp[a*T_ + tid + 256];
  }
  red[tid] = fmaxf(e0, e1);
  __syncthreads();
  for (int s2 = 128; s2 > 0; s2 >>= 1) { if (tid < s2) red[tid] = fmaxf(red[tid], red[tid+s2]); __syncthreads(); }
  float M = red[0];
  __syncthreads();
  int len = P.src_lens[b];
  float p0 = (tid       < len) ? expf(e0 - M) : 0.f;
  float p1 = (tid + 256 < len) ? expf(e1 - M) : 0.f;
  red[tid] = p0 + p1;
  __syncthreads();
  for (int s2 = 128; s2 > 0; s2 >>= 1) { if (tid < s2) red[tid] += red[tid+s2]; __syncthreads(); }
  float S = red[0];
  __syncthreads();
  att_sh[tid]       = p0 / S;
  att_sh[tid + 256] = p1 / S;
  __syncthreads();
  int vl = tid & 63, tq = tid >> 6;
  int v = vs*64 + vl;
  const float* vp = P.value + (size_t)b*T_*VD_ + v;
  float acc = 0.f;
  int t0 = tq*128;
#pragma unroll 8
  for (int t = t0; t < t0 + 128; t++) acc += att_sh[t] * vp[(size_t)t*VD_];
  red[tid] = acc;
  __syncthreads();
  if (tid < 64) P.ctx[b*VD_ + vs*64 + tid] = red[tid] + red[tid+64] + red[tid+128] + red[tid+192];
}

// ---------------- proj GEMM (256 blocks, 2 m-rows each)
__global__ __launch_bounds__(256) void k_proj(DecArgs P) {
  __shared__ float sm[2600];
  int bid = blockIdx.x, tid = threadIdx.x;
  float* Wl   = sm;          // [64][3]
  float* xl   = sm + 192;    // [64][36]
  float* part = sm + 2496;   // [2][36]
  const int kp = tid >> 5, ml = (tid >> 4) & 1, bg = tid & 15;
  float acc0 = 0.f, acc1 = 0.f;

  for (int w = 0; w < 16; w++) {
    __syncthreads();
    if (tid < 32) {
      int r = tid >> 4, i = tid & 15;
      float4 x = *((const float4*)(P.Wm + (size_t)(bid*2+r)*1024) + w*16 + i);
      int kb = i*4;
      Wl[(kb+0)*3+r]=x.x; Wl[(kb+1)*3+r]=x.y; Wl[(kb+2)*3+r]=x.z; Wl[(kb+3)*3+r]=x.w;
    }
    {
      int q = tid*2;
#pragma unroll
      for (int u = 0; u < 2; u++, q++) {
        int b = q >> 4, i = q & 15;
        float4 x = (w < 8) ? *((const float4*)(P.c + b*512) + w*16 + i)
                           : *((const float4*)(P.ctx + b*512) + (w-8)*16 + i);
        int kb = i*4;
        xl[(kb+0)*36+b]=x.x; xl[(kb+1)*36+b]=x.y; xl[(kb+2)*36+b]=x.z; xl[(kb+3)*36+b]=x.w;
      }
    }
    __syncthreads();
#pragma unroll
    for (int kk = 0; kk < 8; kk++) {
      int kl = kp*8 + kk;
      float wv = Wl[kl*3 + ml];
      acc0 += wv * xl[kl*36 + bg*2];
      acc1 += wv * xl[kl*36 + bg*2 + 1];
    }
  }
  __syncthreads();
  for (int rd = 0; rd < 8; rd++) {
    if (kp == rd) {
      float* pr = part + ml*36 + bg*2;
      if (rd == 0) { pr[0] = acc0; pr[1] = acc1; }
      else         { pr[0] += acc0; pr[1] += acc1; }
    }
    __syncthreads();
  }
  if (tid < 64) {
    int ml2 = tid >> 5, b = tid & 31;
    int m = bid*2 + ml2;
    float s = part[ml2*36 + b] + P.bm[m];
    P.projT[m*32 + b] = (s > 0.f) ? s : 0.01f*s;
  }
}

// ---------------- logits chunk (64 v) reg-tiled GEMM + per-chunk partials (500 blocks)
__global__ __launch_bounds__(256) void k_logits(DecArgs P) {
  __shared__ float sm[9600];
  int bid = blockIdx.x, tid = threadIdx.x;
  const int v0 = bid * 64;
  float* Wl   = sm;            // [64k][68]
  float* pl   = sm + 4352;     // [64k][32]
  float* part = sm + 6400;     // [32b][68]
  const int kp = tid >> 5, vg = (tid >> 2) & 7, bg = tid & 3;
  const int sr = tid >> 2, skq = tid & 3;
  float acc[64];
#pragma unroll
  for (int i = 0; i < 64; i++) acc[i] = 0.f;

  const float* wrow = P.W_emb + (size_t)(v0 + sr)*H_ + skq*16;
  const float4* pbase = (const float4*)P.projT;
  float4 t0 = *((const float4*)(wrow + 0));
  float4 t1 = *((const float4*)(wrow + 4));
  float4 t2 = *((const float4*)(wrow + 8));
  float4 t3 = *((const float4*)(wrow + 12));
  float4 u0 = pbase[tid];
  float4 u1 = pbase[tid + 256];

  for (int w = 0; w < 8; w++) {
    __syncthreads();
    int kb = skq*16;
    Wl[(kb+ 0)*68+sr]=t0.x; Wl[(kb+ 1)*68+sr]=t0.y; Wl[(kb+ 2)*68+sr]=t0.z; Wl[(kb+ 3)*68+sr]=t0.w;
    Wl[(kb+ 4)*68+sr]=t1.x; Wl[(kb+ 5)*68+sr]=t1.y; Wl[(kb+ 6)*68+sr]=t1.z; Wl[(kb+ 7)*68+sr]=t1.w;
    Wl[(kb+ 8)*68+sr]=t2.x; Wl[(kb+ 9)*68+sr]=t2.y; Wl[(kb+10)*68+sr]=t2.z; Wl[(kb+11)*68+sr]=t2.w;
    Wl[(kb+12)*68+sr]=t3.x; Wl[(kb+13)*68+sr]=t3.y; Wl[(kb+14)*68+sr]=t3.z; Wl[(kb+15)*68+sr]=t3.w;
    ((float4*)pl)[tid]       = u0;
    ((float4*)pl)[tid + 256] = u1;
    __syncthreads();
    if (w < 7) {
      const float* wn = wrow + (w+1)*64;
      t0 = *((const float4*)(wn + 0));
      t1 = *((const float4*)(wn + 4));
      t2 = *((const float4*)(wn + 8));
      t3 = *((const float4*)(wn + 12));
      u0 = pbase[(w+1)*512 + tid];
      u1 = pbase[(w+1)*512 + tid + 256];
    }
#pragma unroll
    for (int kk = 0; kk < 8; kk++) {
      int kl = kp*8 + kk;
      float4 wv0 = *((const float4*)(Wl + kl*68 + vg*8));
      float4 wv1 = *((const float4*)(Wl + kl*68 + vg*8 + 4));
      float4 pv0 = *((const float4*)(pl + kl*32 + bg*8));
      float4 pv1 = *((const float4*)(pl + kl*32 + bg*8 + 4));
      float wa[8] = {wv0.x,wv0.y,wv0.z,wv0.w,wv1.x,wv1.y,wv1.z,wv1.w};
      float pa[8] = {pv0.x,pv0.y,pv0.z,pv0.w,pv1.x,pv1.y,pv1.z,pv1.w};
#pragma unroll
      for (int i = 0; i < 8; i++)
#pragma unroll
        for (int j = 0; j < 8; j++)
          acc[i*8+j] += wa[i]*pa[j];
    }
  }
  __syncthreads();
  if (kp == 0) {
#pragma unroll
    for (int j = 0; j < 8; j++) {
      int b = bg*8 + j;
      *((float4*)(part + b*68 + vg*8))     = make_float4(acc[0*8+j], acc[1*8+j], acc[2*8+j], acc[3*8+j]);
      *((float4*)(part + b*68 + vg*8 + 4)) = make_float4(acc[4*8+j], acc[5*8+j], acc[6*8+j], acc[7*8+j]);
    }
  }
  __syncthreads();
  for (int rd = 1; rd < 8; rd++) {
    if (kp == rd) {
#pragma unroll
      for (int j = 0; j < 8; j++) {
        int b = bg*8 + j;
        float4* q0 = (float4*)(part + b*68 + vg*8);
        float4* q1 = q0 + 1;
        float4 a0 = *q0, a1 = *q1;
        a0.x += acc[0*8+j]; a0.y += acc[1*8+j]; a0.z += acc[2*8+j]; a0.w += acc[3*8+j];
        a1.x += acc[4*8+j]; a1.y += acc[5*8+j]; a1.z += acc[6*8+j]; a1.w += acc[7*8+j];
        *q0 = a0; *q1 = a1;
      }
    }
    __syncthreads();
  }
  int b = tid >> 3, vq = tid & 7;
  float4 pA = *((const float4*)(part + b*68 + vq*8));
  float4 pB = *((const float4*)(part + b*68 + vq*8 + 4));
  int vb = v0 + vq*8;
  float x[8] = {pA.x,pA.y,pA.z,pA.w,pB.x,pB.y,pB.z,pB.w};
#pragma unroll
  for (int i = 0; i < 8; i++) x[i] += P.b_proj[vb + i];
  *((float4*)(P.logits + (size_t)b*V_ + vb))     = make_float4(x[0],x[1],x[2],x[3]);
  *((float4*)(P.logits + (size_t)b*V_ + vb + 4)) = make_float4(x[4],x[5],x[6],x[7]);
  float m = x[0], s = 1.f; int mi = vb;
#pragma unroll
  for (int i = 1; i < 8; i++) {
    if (x[i] > m) { s = s*expf(m - x[i]) + 1.f; m = x[i]; mi = vb + i; }
    else          { s += expf(x[i] - m); }
  }
  float* rm = sm; float* rs = sm + 256; int* ri = (int*)(sm + 512);
  __syncthreads();   // done with Wl region
  rm[vq*32 + b] = m; rs[vq*32 + b] = s; ri[vq*32 + b] = mi;
  __syncthreads();
  if (tid < 32) {
    int bb = tid;
    float M = rm[bb], S = rs[bb]; int I = ri[bb];
#pragma unroll
    for (int g = 1; g < 8; g++) {
      float m2 = rm[g*32+bb], s2 = rs[g*32+bb]; int i2 = ri[g*32+bb];
      if (m2 > M)       { S = S*expf(M - m2) + s2; M = m2; I = i2; }
      else if (m2 == M) { S += s2; I = min(I, i2); }
      else              { S += s2*expf(m2 - M); }
    }
    P.pm[bid*32 + bb] = M; P.ps[bid*32 + bb] = S; P.pidx[bid*32 + bb] = I;
  }
}

// ---------------- merge chunk partials -> lse[b], idx[b]  (32 blocks, one per b)
__global__ __launch_bounds__(256) void k_merge(DecArgs P) {
  __shared__ float sfm[256], sfs[256];
  __shared__ int   sii[256];
  int b = blockIdx.x, tid = threadIdx.x;
  float M = P.pm[tid*32 + b], S = P.ps[tid*32 + b]; int I = P.pidx[tid*32 + b];
  int c2 = tid + 256;
  if (c2 < NCHUNK) {
    float m2 = P.pm[c2*32+b], s2 = P.ps[c2*32+b]; int i2 = P.pidx[c2*32+b];
    if (m2 > M)       { S = S*expf(M - m2) + s2; M = m2; I = i2; }
    else if (m2 == M) { S += s2; I = min(I, i2); }
    else              { S += s2*expf(m2 - M); }
  }
  sfm[tid] = M; sfs[tid] = S; sii[tid] = I;
  __syncthreads();
  for (int st = 128; st > 0; st >>= 1) {
    if (tid < st) {
      float m1 = sfm[tid], s1 = sfs[tid]; int i1 = sii[tid];
      float m2 = sfm[tid+st], s2 = sfs[tid+st]; int i2 = sii[tid+st];
      float Mn, Sn; int In;
      if (m2 > m1)      { Mn = m2; Sn = s1*expf(m1-m2) + s2; In = i2; }
      else if (m2 < m1) { Mn = m1; Sn = s1 + s2*expf(m2-m1); In = i1; }
      else              { Mn = m1; Sn = s1 + s2; In = min(i1, i2); }
      sfm[tid] = Mn; sfs[tid] = Sn; sii[tid] = In;
    }
    __syncthreads();
  }
  if (tid == 0) { P.lse[b] = sfm[0] + logf(sfs[0]); P.idx[b] = sii[0]; }
}

// ---------------- final out write (step L-1), 256 blocks
__global__ __launch_bounds__(256) void k_finalout(DecArgs P) {
  int bid = blockIdx.x, tid = threadIdx.x;
  int b = bid & 31, vs = bid >> 5;
  float l = P.lse[b];
  const float4* lg = (const float4*)(P.logits + (size_t)b*V_ + vs*4000);
  float4* o4 = (float4*)(P.out + ((size_t)b*P.L + (P.L-1))*V_ + vs*4000);
  for (int i = tid; i < 1000; i += 256) {
    float4 x = lg[i];
    o4[i] = make_float4(x.x-l, x.y-l, x.z-l, x.w-l);
  }
}

extern "C" void kernel_launch(void* const* d_in, const int* in_sizes, int n_in,
                              void* d_out, int out_size, void* d_ws, size_t ws_size,
                              hipStream_t stream) {
  DecArgs P;
  P.key      = (const float*)d_in[0];
  P.value    = (const float*)d_in[1];
  P.src_lens = (const int*)d_in[4];
  P.W_emb    = (const float*)d_in[5];
  P.b_proj   = (const float*)d_in[6];
  P.Wq       = (const float*)d_in[7];
  P.bq       = (const float*)d_in[8];
  P.W_ih     = (const float*)d_in[9];
  P.W_hh     = (const float*)d_in[10];
  P.b_ih     = (const float*)d_in[11];
  P.b_hh     = (const float*)d_in[12];
  P.Wm       = (const float*)d_in[13];
  P.bm       = (const float*)d_in[14];
  P.h00      = (const float*)d_in[15];
  P.c00      = (const float*)d_in[16];
  P.out      = (float*)d_out;
  P.L        = in_sizes[2] / B_;

  float* ws = (float*)d_ws;
  P.hA     = ws; ws += B_*H_;
  P.hB     = ws; ws += B_*H_;
  P.c      = ws; ws += B_*H_;
  P.ctx    = ws; ws += B_*VD_;
  P.projT  = ws; ws += H_*B_;
  P.lse    = ws; ws += 32;
  P.pm     = ws; ws += NCHUNK*B_;
  P.ps     = ws; ws += NCHUNK*B_;
  P.logits = ws; ws += (size_t)B_*V_;
  P.pidx   = (int*)ws; ws += NCHUNK*B_;
  P.idx    = (int*)ws;

  k_init<<<64, 256, 0, stream>>>(P);
  k_att<<<256, 256, 0, stream>>>(P, P.hA);   // prologue attend with h0

  for (int s = 0; s < P.L; s++) {
    const float* hin  = (s & 1) ? P.hB : P.hA;
    float*       hout = (s & 1) ? P.hA : P.hB;
    k_gatesout<<<512, 256, 0, stream>>>(P, hin, hout, s);
    k_att<<<256, 256, 0, stream>>>(P, hout);
    k_proj<<<256, 256, 0, stream>>>(P);
    k_logits<<<NCHUNK, 256, 0, stream>>>(P);
    k_merge<<<32, 256, 0, stream>>>(P);
  }
  k_finalout<<<256, 256, 0, stream>>>(P);
}